// Round 1
// baseline (257.733 us; speedup 1.0000x reference)
//
#include <hip/hip_runtime.h>

// Reference: SNN-style temporal scan over T=16 steps, K=8 nested thresholds.
// Each spatial element is independent; scan carried in registers.
// Arithmetic replicates the numpy/JAX op order exactly (no fast-math, no FMA
// contraction opportunities) so threshold comparisons are bit-exact.

#define T_STEPS 16
#define K_THRESH 8

__global__ __launch_bounds__(256) void snn_scan_kernel(
    const float* __restrict__ x,
    const float* __restrict__ thresh_p,
    float* __restrict__ out,
    int N4)  // number of float4 groups per timestep slice
{
    const int i = blockIdx.x * blockDim.x + threadIdx.x;
    if (i >= N4) return;

    const float th = *thresh_p;
    // lev[k] = thresh / 2^k (exact); thq[k] = 0.75 * lev[k] (single rounded mul,
    // identical to reference's thre_shaped * 0.75)
    float lev[K_THRESH], thq[K_THRESH];
#pragma unroll
    for (int k = 0; k < K_THRESH; ++k) {
        lev[k] = __builtin_ldexpf(th, -k);
        thq[k] = 0.75f * lev[k];
    }

    const float4* __restrict__ xv = (const float4*)x;
    float4* __restrict__ ov = (float4*)out;

    // t = 0 slice: bias; output slice 0 is all zeros
    const float4 b4 = xv[i];
    ov[i] = make_float4(0.f, 0.f, 0.f, 0.f);

    float bias[4] = {b4.x, b4.y, b4.z, b4.w};
    float mem[4]  = {0.f, 0.f, 0.f, 0.f};
    float ein[4]  = {bias[0], bias[1], bias[2], bias[3]};  // exp_in init = bias
    float eout[4] = {0.f, 0.f, 0.f, 0.f};

    // one-ahead prefetch of the next timestep's data
    float4 xi4 = xv[N4 + i];

#pragma unroll
    for (int t = 1; t <= T_STEPS; ++t) {
        const float xi[4] = {xi4.x, xi4.y, xi4.z, xi4.w};
        if (t < T_STEPS) xi4 = xv[(t + 1) * N4 + i];

        const float tf = (float)t;
        float sp[4];
#pragma unroll
        for (int j = 0; j < 4; ++j) {
            // mem = mem + xi - bias + exp_in - exp_out  (left-to-right order)
            float m = (((mem[j] + xi[j]) - bias[j]) + ein[j]) - eout[j];

            // first-fired threshold: smallest k with |m| >= thq[k]
            // (conditions are nested: thq decreases with k, so scanning k=7..0
            //  and overwriting leaves the smallest satisfied k)
            const float a = fabsf(m);
            float mag = 0.f;
#pragma unroll
            for (int k = K_THRESH - 1; k >= 0; --k)
                mag = (a >= thq[k]) ? lev[k] : mag;
            const float s = (m >= 0.f) ? mag : -mag;

            m = m - s;
            ein[j]  = ein[j]  + (xi[j] - bias[j]) / tf;  // IEEE div, matches np
            eout[j] = eout[j] + s / tf;
            mem[j] = m;
            sp[j] = s;
        }
        ov[t * N4 + i] = make_float4(sp[0], sp[1], sp[2], sp[3]);
    }
}

extern "C" void kernel_launch(void* const* d_in, const int* in_sizes, int n_in,
                              void* d_out, int out_size, void* d_ws, size_t ws_size,
                              hipStream_t stream) {
    const float* x       = (const float*)d_in[0];
    const float* thresh  = (const float*)d_in[1];
    // d_in[2] is T (int scalar) == 16, compile-time constant here
    float* out = (float*)d_out;

    const int N  = in_sizes[0] / (T_STEPS + 1);  // elements per timestep slice
    const int N4 = N / 4;                         // float4 groups (N divisible by 4)

    const int block = 256;
    const int grid  = (N4 + block - 1) / block;
    snn_scan_kernel<<<grid, block, 0, stream>>>(x, thresh, out, N4);
}

// Round 2
// 251.415 us; speedup vs baseline: 1.0251x; 1.0251x over previous
//
#include <hip/hip_runtime.h>

// SNN temporal scan, T=16 steps, K=8 nested thresholds. Bit-exact vs numpy f32:
// - mem update keeps reference's left-to-right add order
// - /t kept as IEEE div ONLY where unavoidable (odd t for the ein path);
//   power-of-2 divisions replaced by exact multiplies (identical rounding)
// - spike/t: spike = ±th*2^-k, and rn((th*2^-k)/t) = 2^-k * rn(th/t), so one
//   q_t = th/t per thread replaces a per-element div; products by 2^-k are
//   exact, so FMA contraction cannot change results.
// 2 elements/thread (float2), 8 waves/SIMD, non-temporal streamed stores.

#define T_STEPS 16
#define K_THRESH 8

typedef float v2f __attribute__((ext_vector_type(2)));

__global__ __launch_bounds__(256, 8) void snn_scan_kernel(
    const float* __restrict__ x,
    const float* __restrict__ thresh_p,
    float* __restrict__ out,
    int N2)  // float2 groups per timestep slice
{
    const int i = blockIdx.x * blockDim.x + threadIdx.x;
    if (i >= N2) return;

    const float th = *thresh_p;
    const float thq0 = 0.75f * th;
    // thq[k] = 2^-k * rn(0.75*th)  == reference's rn(0.75 * (th/2^k)) exactly
    float thq[K_THRESH];
#pragma unroll
    for (int k = 0; k < K_THRESH; ++k) thq[k] = __builtin_ldexpf(thq0, -k);

    const v2f* __restrict__ xv = (const v2f*)x;
    v2f* __restrict__ ov = (v2f*)out;

    const v2f b2 = xv[i];
    {
        v2f z; z.x = 0.f; z.y = 0.f;
        __builtin_nontemporal_store(z, ov + i);  // output slice 0 = zeros
    }

    float mem0 = 0.f, mem1 = 0.f;
    const float bias0 = b2.x, bias1 = b2.y;
    float ein0 = bias0, ein1 = bias1;   // exp_in init = bias
    float eout0 = 0.f, eout1 = 0.f;

    v2f xi2 = xv[N2 + i];  // one-ahead prefetch

#pragma unroll
    for (int t = 1; t <= T_STEPS; ++t) {
        const float xi0 = xi2.x, xi1 = xi2.y;
        if (t < T_STEPS) xi2 = xv[(t + 1) * N2 + i];

        const bool tp2 = (t & (t - 1)) == 0;      // compile-time per unrolled iter
        const float rt = 1.0f / (float)t;         // folded constant; used iff tp2
        const float q_t = tp2 ? (th * rt)         // exact (pow2 scale)
                              : (th / (float)t);  // IEEE div, once per thread

        auto stepj = [&](float& mem, float& ein, float& eout,
                         float xi, float bias) -> float {
            // mem = mem + xi - bias + exp_in - exp_out (left-to-right)
            const float m = (((mem + xi) - bias) + ein) - eout;
            const float a = __builtin_fabsf(m);
            // first-fired threshold: smallest k with a >= thq[k]
            // (thq decreasing in k; scan k=7..0, overwrite with smallest hit)
            float sc = 0.f;
#pragma unroll
            for (int k = K_THRESH - 1; k >= 0; --k) {
                const float sck = (float)(1.0 / (double)(1 << k));  // exact 2^-k
                sc = (a >= thq[k]) ? sck : sc;
            }
            const bool pos = (m >= 0.f);
            const float mag = sc * th;            // exact: lev[k] = th*2^-k
            const float s   = pos ? mag : -mag;
            const float sq  = sc * q_t;           // exact: rn(s/t) magnitude
            mem = m - s;
            const float d = xi - bias;
            if (tp2) ein = ein + d * rt;          // exact == d/t for pow2 t
            else     ein = ein + d / (float)t;    // IEEE div (odd t)
            eout = eout + (pos ? sq : -sq);
            return s;
        };

        v2f sp;
        sp.x = stepj(mem0, ein0, eout0, xi0, bias0);
        sp.y = stepj(mem1, ein1, eout1, xi1, bias1);
        __builtin_nontemporal_store(sp, ov + t * N2 + i);
    }
}

extern "C" void kernel_launch(void* const* d_in, const int* in_sizes, int n_in,
                              void* d_out, int out_size, void* d_ws, size_t ws_size,
                              hipStream_t stream) {
    const float* x      = (const float*)d_in[0];
    const float* thresh = (const float*)d_in[1];
    float* out = (float*)d_out;

    const int N  = in_sizes[0] / (T_STEPS + 1);  // elements per timestep slice
    const int N2 = N / 2;                        // float2 groups

    const int block = 256;
    const int grid  = (N2 + block - 1) / block;
    snn_scan_kernel<<<grid, block, 0, stream>>>(x, thresh, out, N2);
}